// Round 7
// baseline (768.014 us; speedup 1.0000x reference)
//
#include <hip/hip_runtime.h>

#define NNODES 100000
#define NEDGES 1600000
#define FIN 128
#define FHID 128
#define FOUT 64

typedef unsigned short u16;
typedef unsigned char u8;
typedef unsigned int u32;
typedef __attribute__((ext_vector_type(8))) short short8;
typedef __attribute__((ext_vector_type(4))) float floatx4;

#define NBUK 391                       // ceil(100000/256)
#define NPAD2 (NBUK * 256)             // 100096 perm entries per graph
#define NSL2 250
#define SLICE2 (NEDGES / NSL2)         // 6400, divisible by 4
#define SP ((size_t)NSL2 * NBUK)       // part table elems per graph
#define NH16 ((size_t)NNODES * FHID)   // u16 elems per graph H/T slice

__device__ __forceinline__ u16 f2bf(float f) {
  u32 u = __float_as_uint(f);
  u32 r = (u + 0x7fffu + ((u >> 16) & 1u)) >> 16;   // RNE
  return (u16)r;
}

__device__ __forceinline__ const int* sel(const int* a, const int* b, const int* c, int z) {
  return z == 0 ? a : (z == 1 ? b : c);
}

// ---------------- CSR build: two-level bucket partition, batched over graphs ----
// blockIdx.z = graph. Buckets of 256 nodes (node>>8). One histogram pass with
// TWO LDS histograms (dst for CSR, src for out-degree) -- zero global atomics.
// Scatter places dst-packed edges (u32) and src low bytes (u8) bucket-major;
// per-bucket kernels finish locally. part/part_src/pes alias H[z]; pe aliases T[z].

__global__ __launch_bounds__(256) void bucket_hist_kernel(
    const int* s0, const int* s1, const int* s2,
    const int* d0, const int* d1, const int* d2,
    u16* __restrict__ Hbase, int E) {
  const int z = blockIdx.z;
  const int* __restrict__ src = sel(s0, s1, s2, z);
  const int* __restrict__ dst = sel(d0, d1, d2, z);
  u32* __restrict__ part = (u32*)(Hbase + (size_t)z * NH16);
  u32* __restrict__ part_src = part + SP;
  __shared__ u32 hd[NBUK], hs[NBUK];
  const int s = blockIdx.x;
  for (int i = threadIdx.x; i < NBUK; i += 256) { hd[i] = 0; hs[i] = 0; }
  __syncthreads();
  const int e0 = s * SLICE2, e1 = min(e0 + SLICE2, E);
  const int i0 = e0 >> 2, i1 = e1 >> 2;
  for (int i = i0 + threadIdx.x; i < i1; i += 256) {
    int4 dv = ((const int4*)dst)[i];
    int4 sv = ((const int4*)src)[i];
    atomicAdd(&hd[(u32)dv.x >> 8], 1u);
    atomicAdd(&hd[(u32)dv.y >> 8], 1u);
    atomicAdd(&hd[(u32)dv.z >> 8], 1u);
    atomicAdd(&hd[(u32)dv.w >> 8], 1u);
    atomicAdd(&hs[(u32)sv.x >> 8], 1u);
    atomicAdd(&hs[(u32)sv.y >> 8], 1u);
    atomicAdd(&hs[(u32)sv.z >> 8], 1u);
    atomicAdd(&hs[(u32)sv.w >> 8], 1u);
  }
  __syncthreads();
  for (int i = threadIdx.x; i < NBUK; i += 256) {
    part[(size_t)s * NBUK + i] = hd[i];
    part_src[(size_t)s * NBUK + i] = hs[i];
  }
}

// grid(2,1,z): block.x 0 scans the dst table, 1 the src table.
__global__ __launch_bounds__(512) void scan_part_kernel(u16* __restrict__ Hbase,
                                                        u32* __restrict__ boff_d,
                                                        u32* __restrict__ bcount_d,
                                                        u32* __restrict__ boff_s,
                                                        u32* __restrict__ bcount_s) {
  const int z = blockIdx.z;
  u32* base = (u32*)(Hbase + (size_t)z * NH16);
  u32* __restrict__ part = blockIdx.x ? base + SP : base;
  u32* __restrict__ boff = (blockIdx.x ? boff_s : boff_d) + (size_t)z * NBUK;
  u32* __restrict__ bcount = (blockIdx.x ? bcount_s : bcount_d) + (size_t)z * NBUK;
  const int b = threadIdx.x;
  u32 run = 0;
  if (b < NBUK) {
#pragma unroll 5
    for (int s = 0; s < NSL2; s++) {
      u32 v = part[(size_t)s * NBUK + b];   // coalesced across threads
      part[(size_t)s * NBUK + b] = run;
      run += v;
    }
  }
  __shared__ u32 sh[512];
  sh[threadIdx.x] = (b < NBUK) ? run : 0;
  __syncthreads();
  for (int d = 1; d < 512; d <<= 1) {
    u32 t = (threadIdx.x >= d) ? sh[threadIdx.x - d] : 0;
    __syncthreads();
    sh[threadIdx.x] += t;
    __syncthreads();
  }
  if (b < NBUK) {
    boff[b] = sh[threadIdx.x] - run;  // exclusive over buckets
    bcount[b] = run;
  }
}

__global__ __launch_bounds__(256) void scatter_kernel(
    const int* s0, const int* s1, const int* s2,
    const int* d0, const int* d1, const int* d2,
    u16* __restrict__ Hbase, u16* __restrict__ Tbase,
    const u32* __restrict__ boff_d, const u32* __restrict__ boff_src, int E) {
  const int z = blockIdx.z;
  const int* __restrict__ src = sel(s0, s1, s2, z);
  const int* __restrict__ dst = sel(d0, d1, d2, z);
  const u32* __restrict__ part = (const u32*)(Hbase + (size_t)z * NH16);
  const u32* __restrict__ part_src = part + SP;
  u8* __restrict__ pes = (u8*)(part_src + SP);
  u32* __restrict__ pe = (u32*)(Tbase + (size_t)z * NH16);
  const u32* __restrict__ boff = boff_d + (size_t)z * NBUK;
  const u32* __restrict__ boff_s = boff_src + (size_t)z * NBUK;
  __shared__ u32 cur[NBUK], curs[NBUK];
  const int s = blockIdx.x;
  for (int i = threadIdx.x; i < NBUK; i += 256) {
    cur[i] = part[(size_t)s * NBUK + i] + boff[i];
    curs[i] = part_src[(size_t)s * NBUK + i] + boff_s[i];
  }
  __syncthreads();
  const int e0 = s * SLICE2, e1 = min(e0 + SLICE2, E);
  const int i0 = e0 >> 2, i1 = e1 >> 2;
  for (int i = i0 + threadIdx.x; i < i1; i += 256) {
    int4 sv = ((const int4*)src)[i];
    int4 dv = ((const int4*)dst)[i];
    u32 p;
    p = atomicAdd(&cur[(u32)dv.x >> 8], 1u); pe[p] = ((u32)sv.x << 8) | ((u32)dv.x & 255u);
    p = atomicAdd(&cur[(u32)dv.y >> 8], 1u); pe[p] = ((u32)sv.y << 8) | ((u32)dv.y & 255u);
    p = atomicAdd(&cur[(u32)dv.z >> 8], 1u); pe[p] = ((u32)sv.z << 8) | ((u32)dv.z & 255u);
    p = atomicAdd(&cur[(u32)dv.w >> 8], 1u); pe[p] = ((u32)sv.w << 8) | ((u32)dv.w & 255u);
    p = atomicAdd(&curs[(u32)sv.x >> 8], 1u); pes[p] = (u8)((u32)sv.x & 255u);
    p = atomicAdd(&curs[(u32)sv.y >> 8], 1u); pes[p] = (u8)((u32)sv.y & 255u);
    p = atomicAdd(&curs[(u32)sv.z >> 8], 1u); pes[p] = (u8)((u32)sv.z & 255u);
    p = atomicAdd(&curs[(u32)sv.w >> 8], 1u); pes[p] = (u8)((u32)sv.w & 255u);
  }
}

// per-bucket finish. blockIdx.y==0: localized CSR build + offs/deg/norm_dst +
// in-bucket degree counting-sort -> perm (degree-uniform spmm blocks).
// blockIdx.y==1: src out-degree count -> norm_src.
__global__ __launch_bounds__(256) void bucket_finish_kernel(
    const u16* __restrict__ Tbase, const u16* __restrict__ Hbase,
    const u32* __restrict__ boffb, const u32* __restrict__ bcountb,
    const u32* __restrict__ boff_sb, const u32* __restrict__ bcount_sb,
    int* __restrict__ csrb, int* __restrict__ offsb, int* __restrict__ degb,
    float* __restrict__ ndb, float* __restrict__ nsb, int* __restrict__ permb, int n) {
  const int z = blockIdx.z;
  const int b = blockIdx.x;
  const int t = threadIdx.x;
  if (blockIdx.y == 1) {
    // ---- src out-degree count ----
    const u32* partb = (const u32*)(Hbase + (size_t)z * NH16);
    const u8* __restrict__ pes = (const u8*)(partb + 2 * SP);
    const u32* boff = boff_sb + (size_t)z * NBUK;
    const u32* bcount = bcount_sb + (size_t)z * NBUK;
    float* __restrict__ norm_src = nsb + (size_t)z * NNODES;
    const int beg = (int)boff[b];
    const int cnt = (int)bcount[b];
    __shared__ int hh[256];
    hh[t] = 0;
    __syncthreads();
    for (int i = t; i < cnt; i += 256) atomicAdd(&hh[pes[beg + i]], 1);
    __syncthreads();
    const int node = b * 256 + t;
    if (node < n) norm_src[node] = rsqrtf(fmaxf((float)hh[t], 1.0f));
    return;
  }
  // ---- CSR build ----
  const u32* __restrict__ pe = (const u32*)(Tbase + (size_t)z * NH16);
  int* __restrict__ csr = csrb + (size_t)z * NEDGES;
  int* __restrict__ offs = offsb + (size_t)z * NNODES;
  int* __restrict__ deg_dst = degb + (size_t)z * NNODES;
  float* __restrict__ norm_dst = ndb + (size_t)z * NNODES;
  int* __restrict__ perm = permb + (size_t)z * NPAD2;
  const u32* boff = boffb + (size_t)z * NBUK;
  const u32* bcount = bcountb + (size_t)z * NBUK;
  const int beg = (int)boff[b];
  const int cnt = (int)bcount[b];
  __shared__ int h[256], loc[256];
  h[t] = 0;
  __syncthreads();
  for (int i = t; i < cnt; i += 256) atomicAdd(&h[pe[beg + i] & 255u], 1);
  __syncthreads();
  const int myc = h[t];
  loc[t] = myc;
  __syncthreads();
  for (int d = 1; d < 256; d <<= 1) {
    int v = (t >= d) ? loc[t - d] : 0;
    __syncthreads();
    loc[t] += v;
    __syncthreads();
  }
  const int start = beg + loc[t] - myc;   // exclusive within bucket
  const int node = b * 256 + t;
  if (node < n) {
    offs[node] = start;
    deg_dst[node] = myc;
    norm_dst[node] = rsqrtf(fmaxf((float)myc, 1.0f));
  }
  // ---- in-bucket counting sort by degree -> perm ----
  __shared__ int dh[64], dbase[64], cnt2[64];
  const int dg = myc > 63 ? 63 : myc;   // invalid nodes have myc==0
  if (t < 64) { dh[t] = 0; cnt2[t] = 0; }
  __syncthreads();
  atomicAdd(&dh[dg], 1);
  __syncthreads();
  if (t < 64) dbase[t] = dh[t];
  __syncthreads();
  for (int d = 1; d < 64; d <<= 1) {
    int v = (t >= d && t < 64) ? dbase[t - d] : 0;
    __syncthreads();
    if (t < 64) dbase[t] += v;
    __syncthreads();
  }
  const int rank = dbase[dg] - dh[dg] + atomicAdd(&cnt2[dg], 1);
  perm[b * 256 + rank] = node;
  __syncthreads();
  h[t] = start;          // cursors
  __syncthreads();
  for (int i = t; i < cnt; i += 256) {
    u32 v = pe[beg + i];
    int p = atomicAdd(&h[v & 255u], 1);
    csr[p] = (int)(v >> 8);     // writes localized to this bucket's ~16KB segment
  }
}

// ---- MFMA GEMM: Yb[n,c] = bf16( norm[n] * sum_k X[n,k] * W[k,c] ) ----
// 64x64 tile, K=128 in LDS (bf16, padded stride 136). 4 waves x 16 rows;
// A-frags in regs; mfma_f32_16x16x32_bf16, fp32 accum. blockIdx.z = graph.

#define XP 136   // padded LDS row stride in u16

template <int CTOT, bool IN_BF16>
__global__ __launch_bounds__(256) void gemm_mfma(const void* X0, const void* X1,
                                                 const void* X2,
                                                 const float* __restrict__ W,
                                                 const float* __restrict__ normb,
                                                 u16* __restrict__ Yb, int nrows) {
  const int z = blockIdx.z;
  const void* __restrict__ Xv = z == 0 ? X0 : (z == 1 ? X1 : X2);
  const float* __restrict__ norm = normb + (size_t)z * NNODES;
  u16* __restrict__ Y = Yb + (size_t)z * NNODES * CTOT;
  __shared__ u16 Xs[64 * XP];   // 17408 B
  __shared__ u16 Wt[64 * XP];   // 17408 B, Wt[n][k] = W[k][col0+n]
  __shared__ float norm_s[64];
  const int tid = threadIdx.x;
  const int row0 = blockIdx.x * 64;
  const int col0 = blockIdx.y * 64;

  if constexpr (IN_BF16) {
    const u16* X = (const u16*)Xv;
    for (int i = tid; i < 64 * 16; i += 256) {       // 16 uint4 per row
      int r = i >> 4, k8 = (i & 15) * 8;
      int gr = row0 + r;
      uint4 v = make_uint4(0u, 0u, 0u, 0u);
      if (gr < nrows) v = *(const uint4*)&X[(size_t)gr * 128 + k8];
      *(uint4*)&Xs[r * XP + k8] = v;
    }
  } else {
    const float* X = (const float*)Xv;
    for (int i = tid; i < 64 * 32; i += 256) {       // 32 float4 per row
      int r = i >> 5, k4 = (i & 31) * 4;
      int gr = row0 + r;
      ushort4 o = make_ushort4(0, 0, 0, 0);
      if (gr < nrows) {
        float4 v = *(const float4*)&X[(size_t)gr * 128 + k4];
        o.x = f2bf(v.x); o.y = f2bf(v.y); o.z = f2bf(v.z); o.w = f2bf(v.w);
      }
      *(ushort4*)&Xs[r * XP + k4] = o;
    }
  }
  for (int i = tid; i < 128 * 16; i += 256) {        // K x 16 float4-groups
    int k = i >> 4, c4 = (i & 15) * 4;
    float4 v = *(const float4*)&W[(size_t)k * CTOT + col0 + c4];
    Wt[(c4 + 0) * XP + k] = f2bf(v.x);
    Wt[(c4 + 1) * XP + k] = f2bf(v.y);
    Wt[(c4 + 2) * XP + k] = f2bf(v.z);
    Wt[(c4 + 3) * XP + k] = f2bf(v.w);
  }
  if (tid < 64) norm_s[tid] = (row0 + tid < nrows) ? norm[row0 + tid] : 0.f;
  __syncthreads();

  const int w = tid >> 6, lane = tid & 63;
  const int quad = lane >> 4, r16 = lane & 15;
  const int arow = w * 16 + r16;

  short8 a[4];
#pragma unroll
  for (int kc = 0; kc < 4; kc++)
    a[kc] = *(const short8*)&Xs[arow * XP + kc * 32 + quad * 8];

#pragma unroll
  for (int nc = 0; nc < 4; nc++) {
    floatx4 acc = {0.f, 0.f, 0.f, 0.f};
#pragma unroll
    for (int kc = 0; kc < 4; kc++) {
      short8 b = *(const short8*)&Wt[(nc * 16 + r16) * XP + kc * 32 + quad * 8];
      acc = __builtin_amdgcn_mfma_f32_16x16x32_bf16(a[kc], b, acc, 0, 0, 0);
    }
#pragma unroll
    for (int i = 0; i < 4; i++) {
      int lr = w * 16 + quad * 4 + i;     // C/D: row = quad*4+reg, col = r16
      int gr = row0 + lr;
      if (gr < nrows)
        Y[(size_t)gr * CTOT + col0 + nc * 16 + r16] = f2bf(acc[i] * norm_s[lr]);
    }
  }
}

// ---- SpMM: Y[n,:] = relu?( (sum_{e: dst=n} Hb[src[e],:]) * norm_dst[n] + b ) ----
// bf16 gather, fp32 accumulate, 2-stage pipelined 4-edge batches. Nodes are
// processed in degree-sorted order (perm, per-bucket counting sort) so each
// block's 16/32 nodes have near-equal degree -> no tail-idle lanes.

__device__ __forceinline__ void acc_row(float* acc, uint4 p) {
  acc[0] += __uint_as_float(p.x << 16);
  acc[1] += __uint_as_float(p.x & 0xffff0000u);
  acc[2] += __uint_as_float(p.y << 16);
  acc[3] += __uint_as_float(p.y & 0xffff0000u);
  acc[4] += __uint_as_float(p.z << 16);
  acc[5] += __uint_as_float(p.z & 0xffff0000u);
  acc[6] += __uint_as_float(p.w << 16);
  acc[7] += __uint_as_float(p.w & 0xffff0000u);
}

template <int F, bool RELU, bool OUT_BF16>
__global__ __launch_bounds__(256) void spmm_bf16(const u16* __restrict__ Hbase,
                                                 const int* __restrict__ offsb,
                                                 const int* __restrict__ degb,
                                                 const int* __restrict__ csrb,
                                                 const float* __restrict__ ndb,
                                                 const float* __restrict__ bias,
                                                 const int* __restrict__ permb,
                                                 void* __restrict__ Yv, int n) {
  const int z = blockIdx.z;
  const u16* __restrict__ Hb = Hbase + (size_t)z * NNODES * F;
  const int* __restrict__ offs = offsb + (size_t)z * NNODES;
  const int* __restrict__ deg = degb + (size_t)z * NNODES;
  const int* __restrict__ csr = csrb + (size_t)z * NEDGES;
  const float* __restrict__ norm_dst = ndb + (size_t)z * NNODES;
  const int* __restrict__ perm = permb + (size_t)z * NPAD2;
  constexpr int TPN = F / 8;        // threads per node (8 bf16 = 16 B per lane)
  constexpr int NPB = 256 / TPN;    // nodes per block
  int idx = blockIdx.x * NPB + threadIdx.x / TPN;
  if (idx >= NPAD2) return;
  int node = perm[idx];
  if (node >= n) return;            // padding entries in last bucket
  int f0 = (threadIdx.x % TPN) * 8;
  int beg = offs[node];
  int end = beg + deg[node];
  const u16* __restrict__ Hp = Hb + f0;
  float acc[8] = {};
  int e = beg;
  int nfull = (end - beg) >> 2;
  if (nfull > 0) {
    int sv[4]; uint4 p[4];
#pragma unroll
    for (int j = 0; j < 4; j++) sv[j] = csr[e + j];
#pragma unroll
    for (int j = 0; j < 4; j++) p[j] = *(const uint4*)&Hp[(size_t)sv[j] * F];
    for (int b = 1; b < nfull; b++) {
      e += 4;
      int s2[4]; uint4 q[4];
#pragma unroll
      for (int j = 0; j < 4; j++) s2[j] = csr[e + j];
#pragma unroll
      for (int j = 0; j < 4; j++) q[j] = *(const uint4*)&Hp[(size_t)s2[j] * F];
#pragma unroll
      for (int j = 0; j < 4; j++) acc_row(acc, p[j]);
#pragma unroll
      for (int j = 0; j < 4; j++) p[j] = q[j];
    }
#pragma unroll
    for (int j = 0; j < 4; j++) acc_row(acc, p[j]);
    e += 4;
  }
  for (; e < end; e++) {
    int s = csr[e];
    uint4 p = *(const uint4*)&Hp[(size_t)s * F];
    acc_row(acc, p);
  }
  float nd = norm_dst[node];
  float o[8];
#pragma unroll
  for (int i = 0; i < 8; i++) {
    o[i] = fmaf(acc[i], nd, bias[f0 + i]);
    if (RELU) o[i] = fmaxf(o[i], 0.f);
  }
  if constexpr (OUT_BF16) {
    u16* Y = (u16*)Yv + (size_t)z * NNODES * F;
    uint4 pk;
    pk.x = (u32)f2bf(o[0]) | ((u32)f2bf(o[1]) << 16);
    pk.y = (u32)f2bf(o[2]) | ((u32)f2bf(o[3]) << 16);
    pk.z = (u32)f2bf(o[4]) | ((u32)f2bf(o[5]) << 16);
    pk.w = (u32)f2bf(o[6]) | ((u32)f2bf(o[7]) << 16);
    *(uint4*)&Y[(size_t)node * F + f0] = pk;
  } else {
    float* Y = (float*)Yv + (size_t)z * NNODES * F;
    *(float4*)&Y[(size_t)node * F + f0] = make_float4(o[0], o[1], o[2], o[3]);
    *(float4*)&Y[(size_t)node * F + f0 + 4] = make_float4(o[4], o[5], o[6], o[7]);
  }
}

// ---------------- driver ----------------
// All phases batched over the 3 graphs via gridDim.z=3 (8 launches total),
// guarded by ws_size; falls back to the proven per-graph sequential path.

extern "C" void kernel_launch(void* const* d_in, const int* in_sizes, int n_in,
                              void* d_out, int out_size, void* d_ws, size_t ws_size,
                              hipStream_t stream) {
  const int N = NNODES;
  const int E = NEDGES;
  const float* W1 = (const float*)d_in[9];
  const float* b1 = (const float*)d_in[10];
  const float* W2 = (const float*)d_in[11];
  const float* b2 = (const float*)d_in[12];

  const size_t HBYTES = NH16 * 2;   // 25.6 MB per graph

  auto need_for = [&](size_t NG) -> size_t {
    size_t o = 0;
    auto al = [&](size_t b) { o = (o + b + 255) & ~(size_t)255; };
    al(NG * N * 4);        // deg_dst
    al(NG * N * 4);        // norm_src
    al(NG * N * 4);        // norm_dst
    al(NG * N * 4);        // offs
    al(NG * NBUK * 4);     // boff
    al(NG * NBUK * 4);     // bcount
    al(NG * NBUK * 4);     // boff_s
    al(NG * NBUK * 4);     // bcount_s
    al(NG * (size_t)NPAD2 * 4); // perm
    al(NG * (size_t)E * 4);// csr
    al(NG * HBYTES);       // H
    al(NG * HBYTES);       // T
    return o;
  };
  const bool batched = ws_size >= need_for(3);
  const size_t NG = batched ? 3 : 1;

  char* ws = (char*)d_ws;
  size_t off = 0;
  auto alloc = [&](size_t bytes) -> void* {
    void* p = ws + off;
    off += (bytes + 255) & ~(size_t)255;
    return p;
  };
  int* deg_dst = (int*)alloc(NG * N * 4);
  float* norm_src = (float*)alloc(NG * N * 4);
  float* norm_dst = (float*)alloc(NG * N * 4);
  int* offs = (int*)alloc(NG * N * 4);
  u32* boff = (u32*)alloc(NG * NBUK * 4);
  u32* bcount = (u32*)alloc(NG * NBUK * 4);
  u32* boff_s = (u32*)alloc(NG * NBUK * 4);
  u32* bcount_s = (u32*)alloc(NG * NBUK * 4);
  int* perm = (int*)alloc(NG * (size_t)NPAD2 * 4);
  int* csr = (int*)alloc(NG * (size_t)E * 4);
  u16* H = (u16*)alloc(NG * HBYTES);
  u16* T = (u16*)alloc(NG * HBYTES);

  const int gemm_rb = (N + 63) / 64;    // 1563
  const int nb1 = NPAD2 / 16;           // 6256 (F=128: 16 nodes/block)
  const int nb2 = NPAD2 / 32;           // 3128 (F=64:  32 nodes/block)

  auto run = [&](const int* s0, const int* s1, const int* s2,
                 const int* d0, const int* d1, const int* d2,
                 const float* f0, const float* f1, const float* f2,
                 const void* x20, const void* x21, const void* x22,
                 void* zoutv, unsigned gz) {
    bucket_hist_kernel<<<dim3(NSL2, 1, gz), 256, 0, stream>>>(s0, s1, s2, d0, d1, d2, H, E);
    scan_part_kernel<<<dim3(2, 1, gz), 512, 0, stream>>>(H, boff, bcount, boff_s, bcount_s);
    scatter_kernel<<<dim3(NSL2, 1, gz), 256, 0, stream>>>(s0, s1, s2, d0, d1, d2,
                                                          H, T, boff, boff_s, E);
    bucket_finish_kernel<<<dim3(NBUK, 2, gz), 256, 0, stream>>>(
        T, H, boff, bcount, boff_s, bcount_s, csr, offs, deg_dst, norm_dst,
        norm_src, perm, N);
    // layer 1: H = bf16((feat @ W1)*norm_src); T = bf16(relu(spmm(H)*nd + b1))
    gemm_mfma<FHID, false><<<dim3(gemm_rb, FHID / 64, gz), 256, 0, stream>>>(
        f0, f1, f2, W1, norm_src, H, N);
    spmm_bf16<FHID, true, true><<<dim3(nb1, 1, gz), 256, 0, stream>>>(
        H, offs, deg_dst, csr, norm_dst, b1, perm, T, N);
    // layer 2: H = bf16((T @ W2)*norm_src); z = spmm(H)*nd + b2 (fp32)
    gemm_mfma<FOUT, true><<<dim3(gemm_rb, FOUT / 64, gz), 256, 0, stream>>>(
        x20, x21, x22, W2, norm_src, H, N);
    spmm_bf16<FOUT, false, false><<<dim3(nb2, 1, gz), 256, 0, stream>>>(
        H, offs, deg_dst, csr, norm_dst, b2, perm, d_out ? zoutv : zoutv, N);
  };

  if (batched) {
    run((const int*)d_in[1], (const int*)d_in[4], (const int*)d_in[7],
        (const int*)d_in[2], (const int*)d_in[5], (const int*)d_in[8],
        (const float*)d_in[0], (const float*)d_in[3], (const float*)d_in[6],
        T, T + NH16, T + 2 * NH16,
        d_out, 3);
  } else {
    for (int g = 0; g < 3; g++) {
      const float* feat = (const float*)d_in[3 * g + 0];
      const int* src = (const int*)d_in[3 * g + 1];
      const int* dst = (const int*)d_in[3 * g + 2];
      float* zout = (float*)d_out + (size_t)g * N * FOUT;
      run(src, src, src, dst, dst, dst, feat, feat, feat, T, T, T, zout, 1);
    }
  }
}

// Round 8
// 698.470 us; speedup vs baseline: 1.0996x; 1.0996x over previous
//
#include <hip/hip_runtime.h>

#define NNODES 100000
#define NEDGES 1600000
#define FIN 128
#define FHID 128
#define FOUT 64

typedef unsigned short u16;
typedef unsigned char u8;
typedef unsigned int u32;
typedef __attribute__((ext_vector_type(8))) short short8;
typedef __attribute__((ext_vector_type(4))) float floatx4;

#define NBUK 391                       // ceil(100000/256)
#define NSL2 250
#define SLICE2 (NEDGES / NSL2)         // 6400, divisible by 4
#define SP ((size_t)NSL2 * NBUK)       // part table elems per graph
#define NH16 ((size_t)NNODES * FHID)   // u16 elems per graph H/T slice

__device__ __forceinline__ u16 f2bf(float f) {
  u32 u = __float_as_uint(f);
  u32 r = (u + 0x7fffu + ((u >> 16) & 1u)) >> 16;   // RNE
  return (u16)r;
}

__device__ __forceinline__ const int* sel(const int* a, const int* b, const int* c, int z) {
  return z == 0 ? a : (z == 1 ? b : c);
}

// ---------------- CSR build: two-level bucket partition, batched over graphs ----
// blockIdx.z = graph. Buckets of 256 nodes (node>>8). One histogram pass with
// TWO LDS histograms (dst for CSR, src for out-degree) -- zero global atomics.
// Scatter places dst-packed edges (u32) and src low bytes (u8) bucket-major;
// per-bucket kernels finish locally. part/part_src/pes alias H[z]; pe aliases T[z].

__global__ __launch_bounds__(256) void bucket_hist_kernel(
    const int* s0, const int* s1, const int* s2,
    const int* d0, const int* d1, const int* d2,
    u16* __restrict__ Hbase, int E) {
  const int z = blockIdx.z;
  const int* __restrict__ src = sel(s0, s1, s2, z);
  const int* __restrict__ dst = sel(d0, d1, d2, z);
  u32* __restrict__ part = (u32*)(Hbase + (size_t)z * NH16);
  u32* __restrict__ part_src = part + SP;
  __shared__ u32 hd[NBUK], hs[NBUK];
  const int s = blockIdx.x;
  for (int i = threadIdx.x; i < NBUK; i += 256) { hd[i] = 0; hs[i] = 0; }
  __syncthreads();
  const int e0 = s * SLICE2, e1 = min(e0 + SLICE2, E);
  const int i0 = e0 >> 2, i1 = e1 >> 2;
  for (int i = i0 + threadIdx.x; i < i1; i += 256) {
    int4 dv = ((const int4*)dst)[i];
    int4 sv = ((const int4*)src)[i];
    atomicAdd(&hd[(u32)dv.x >> 8], 1u);
    atomicAdd(&hd[(u32)dv.y >> 8], 1u);
    atomicAdd(&hd[(u32)dv.z >> 8], 1u);
    atomicAdd(&hd[(u32)dv.w >> 8], 1u);
    atomicAdd(&hs[(u32)sv.x >> 8], 1u);
    atomicAdd(&hs[(u32)sv.y >> 8], 1u);
    atomicAdd(&hs[(u32)sv.z >> 8], 1u);
    atomicAdd(&hs[(u32)sv.w >> 8], 1u);
  }
  __syncthreads();
  for (int i = threadIdx.x; i < NBUK; i += 256) {
    part[(size_t)s * NBUK + i] = hd[i];
    part_src[(size_t)s * NBUK + i] = hs[i];
  }
}

// grid(2,1,z): block.x 0 scans the dst table, 1 the src table.
__global__ __launch_bounds__(512) void scan_part_kernel(u16* __restrict__ Hbase,
                                                        u32* __restrict__ boff_d,
                                                        u32* __restrict__ bcount_d,
                                                        u32* __restrict__ boff_s,
                                                        u32* __restrict__ bcount_s) {
  const int z = blockIdx.z;
  u32* base = (u32*)(Hbase + (size_t)z * NH16);
  u32* __restrict__ part = blockIdx.x ? base + SP : base;
  u32* __restrict__ boff = (blockIdx.x ? boff_s : boff_d) + (size_t)z * NBUK;
  u32* __restrict__ bcount = (blockIdx.x ? bcount_s : bcount_d) + (size_t)z * NBUK;
  const int b = threadIdx.x;
  u32 run = 0;
  if (b < NBUK) {
#pragma unroll 5
    for (int s = 0; s < NSL2; s++) {
      u32 v = part[(size_t)s * NBUK + b];   // coalesced across threads
      part[(size_t)s * NBUK + b] = run;
      run += v;
    }
  }
  __shared__ u32 sh[512];
  sh[threadIdx.x] = (b < NBUK) ? run : 0;
  __syncthreads();
  for (int d = 1; d < 512; d <<= 1) {
    u32 t = (threadIdx.x >= d) ? sh[threadIdx.x - d] : 0;
    __syncthreads();
    sh[threadIdx.x] += t;
    __syncthreads();
  }
  if (b < NBUK) {
    boff[b] = sh[threadIdx.x] - run;  // exclusive over buckets
    bcount[b] = run;
  }
}

__global__ __launch_bounds__(256) void scatter_kernel(
    const int* s0, const int* s1, const int* s2,
    const int* d0, const int* d1, const int* d2,
    u16* __restrict__ Hbase, u16* __restrict__ Tbase,
    const u32* __restrict__ boff_d, const u32* __restrict__ boff_src, int E) {
  const int z = blockIdx.z;
  const int* __restrict__ src = sel(s0, s1, s2, z);
  const int* __restrict__ dst = sel(d0, d1, d2, z);
  const u32* __restrict__ part = (const u32*)(Hbase + (size_t)z * NH16);
  const u32* __restrict__ part_src = part + SP;
  u8* __restrict__ pes = (u8*)(part_src + SP);
  u32* __restrict__ pe = (u32*)(Tbase + (size_t)z * NH16);
  const u32* __restrict__ boff = boff_d + (size_t)z * NBUK;
  const u32* __restrict__ boff_s = boff_src + (size_t)z * NBUK;
  __shared__ u32 cur[NBUK], curs[NBUK];
  const int s = blockIdx.x;
  for (int i = threadIdx.x; i < NBUK; i += 256) {
    cur[i] = part[(size_t)s * NBUK + i] + boff[i];
    curs[i] = part_src[(size_t)s * NBUK + i] + boff_s[i];
  }
  __syncthreads();
  const int e0 = s * SLICE2, e1 = min(e0 + SLICE2, E);
  const int i0 = e0 >> 2, i1 = e1 >> 2;
  for (int i = i0 + threadIdx.x; i < i1; i += 256) {
    int4 sv = ((const int4*)src)[i];
    int4 dv = ((const int4*)dst)[i];
    u32 p;
    p = atomicAdd(&cur[(u32)dv.x >> 8], 1u); pe[p] = ((u32)sv.x << 8) | ((u32)dv.x & 255u);
    p = atomicAdd(&cur[(u32)dv.y >> 8], 1u); pe[p] = ((u32)sv.y << 8) | ((u32)dv.y & 255u);
    p = atomicAdd(&cur[(u32)dv.z >> 8], 1u); pe[p] = ((u32)sv.z << 8) | ((u32)dv.z & 255u);
    p = atomicAdd(&cur[(u32)dv.w >> 8], 1u); pe[p] = ((u32)sv.w << 8) | ((u32)dv.w & 255u);
    p = atomicAdd(&curs[(u32)sv.x >> 8], 1u); pes[p] = (u8)((u32)sv.x & 255u);
    p = atomicAdd(&curs[(u32)sv.y >> 8], 1u); pes[p] = (u8)((u32)sv.y & 255u);
    p = atomicAdd(&curs[(u32)sv.z >> 8], 1u); pes[p] = (u8)((u32)sv.z & 255u);
    p = atomicAdd(&curs[(u32)sv.w >> 8], 1u); pes[p] = (u8)((u32)sv.w & 255u);
  }
}

// per-bucket finish. blockIdx.y==0: localized CSR build + offs/deg/norm_dst.
// blockIdx.y==1: src out-degree count -> norm_src. (No degree sort: round-7
// measured it as a regression -- heterogeneous block durations.)
__global__ __launch_bounds__(256) void bucket_finish_kernel(
    const u16* __restrict__ Tbase, const u16* __restrict__ Hbase,
    const u32* __restrict__ boffb, const u32* __restrict__ bcountb,
    const u32* __restrict__ boff_sb, const u32* __restrict__ bcount_sb,
    int* __restrict__ csrb, int* __restrict__ offsb, int* __restrict__ degb,
    float* __restrict__ ndb, float* __restrict__ nsb, int n) {
  const int z = blockIdx.z;
  const int b = blockIdx.x;
  const int t = threadIdx.x;
  if (blockIdx.y == 1) {
    const u32* partb = (const u32*)(Hbase + (size_t)z * NH16);
    const u8* __restrict__ pes = (const u8*)(partb + 2 * SP);
    const u32* boff = boff_sb + (size_t)z * NBUK;
    const u32* bcount = bcount_sb + (size_t)z * NBUK;
    float* __restrict__ norm_src = nsb + (size_t)z * NNODES;
    const int beg = (int)boff[b];
    const int cnt = (int)bcount[b];
    __shared__ int hh[256];
    hh[t] = 0;
    __syncthreads();
    for (int i = t; i < cnt; i += 256) atomicAdd(&hh[pes[beg + i]], 1);
    __syncthreads();
    const int node = b * 256 + t;
    if (node < n) norm_src[node] = rsqrtf(fmaxf((float)hh[t], 1.0f));
    return;
  }
  const u32* __restrict__ pe = (const u32*)(Tbase + (size_t)z * NH16);
  int* __restrict__ csr = csrb + (size_t)z * NEDGES;
  int* __restrict__ offs = offsb + (size_t)z * NNODES;
  int* __restrict__ deg_dst = degb + (size_t)z * NNODES;
  float* __restrict__ norm_dst = ndb + (size_t)z * NNODES;
  const u32* boff = boffb + (size_t)z * NBUK;
  const u32* bcount = bcountb + (size_t)z * NBUK;
  const int beg = (int)boff[b];
  const int cnt = (int)bcount[b];
  __shared__ int h[256], loc[256];
  h[t] = 0;
  __syncthreads();
  for (int i = t; i < cnt; i += 256) atomicAdd(&h[pe[beg + i] & 255u], 1);
  __syncthreads();
  const int myc = h[t];
  loc[t] = myc;
  __syncthreads();
  for (int d = 1; d < 256; d <<= 1) {
    int v = (t >= d) ? loc[t - d] : 0;
    __syncthreads();
    loc[t] += v;
    __syncthreads();
  }
  const int start = beg + loc[t] - myc;   // exclusive within bucket
  const int node = b * 256 + t;
  if (node < n) {
    offs[node] = start;
    deg_dst[node] = myc;
    norm_dst[node] = rsqrtf(fmaxf((float)myc, 1.0f));
  }
  __syncthreads();
  h[t] = start;          // cursors
  __syncthreads();
  for (int i = t; i < cnt; i += 256) {
    u32 v = pe[beg + i];
    int p = atomicAdd(&h[v & 255u], 1);
    csr[p] = (int)(v >> 8);     // writes localized to this bucket's ~16KB segment
  }
}

// ---- MFMA GEMM: Yb[n,c] = bf16( norm[n] * sum_k X[n,k] * W[k,c] ) ----
// 64x64 tile, K=128 in LDS (bf16, padded stride 136). 4 waves x 16 rows;
// A-frags in regs; mfma_f32_16x16x32_bf16, fp32 accum. blockIdx.z = graph.

#define XP 136   // padded LDS row stride in u16

template <int CTOT, bool IN_BF16>
__global__ __launch_bounds__(256) void gemm_mfma(const void* X0, const void* X1,
                                                 const void* X2,
                                                 const float* __restrict__ W,
                                                 const float* __restrict__ normb,
                                                 u16* __restrict__ Yb, int nrows) {
  const int z = blockIdx.z;
  const void* __restrict__ Xv = z == 0 ? X0 : (z == 1 ? X1 : X2);
  const float* __restrict__ norm = normb + (size_t)z * NNODES;
  u16* __restrict__ Y = Yb + (size_t)z * NH16;
  __shared__ u16 Xs[64 * XP];   // 17408 B
  __shared__ u16 Wt[64 * XP];   // 17408 B, Wt[n][k] = W[k][col0+n]
  __shared__ float norm_s[64];
  const int tid = threadIdx.x;
  const int row0 = blockIdx.x * 64;
  const int col0 = blockIdx.y * 64;

  if constexpr (IN_BF16) {
    const u16* X = (const u16*)Xv;
    for (int i = tid; i < 64 * 16; i += 256) {       // 16 uint4 per row
      int r = i >> 4, k8 = (i & 15) * 8;
      int gr = row0 + r;
      uint4 v = make_uint4(0u, 0u, 0u, 0u);
      if (gr < nrows) v = *(const uint4*)&X[(size_t)gr * 128 + k8];
      *(uint4*)&Xs[r * XP + k8] = v;
    }
  } else {
    const float* X = (const float*)Xv;
    for (int i = tid; i < 64 * 32; i += 256) {       // 32 float4 per row
      int r = i >> 5, k4 = (i & 31) * 4;
      int gr = row0 + r;
      ushort4 o = make_ushort4(0, 0, 0, 0);
      if (gr < nrows) {
        float4 v = *(const float4*)&X[(size_t)gr * 128 + k4];
        o.x = f2bf(v.x); o.y = f2bf(v.y); o.z = f2bf(v.z); o.w = f2bf(v.w);
      }
      *(ushort4*)&Xs[r * XP + k4] = o;
    }
  }
  for (int i = tid; i < 128 * 16; i += 256) {        // K x 16 float4-groups
    int k = i >> 4, c4 = (i & 15) * 4;
    float4 v = *(const float4*)&W[(size_t)k * CTOT + col0 + c4];
    Wt[(c4 + 0) * XP + k] = f2bf(v.x);
    Wt[(c4 + 1) * XP + k] = f2bf(v.y);
    Wt[(c4 + 2) * XP + k] = f2bf(v.z);
    Wt[(c4 + 3) * XP + k] = f2bf(v.w);
  }
  if (tid < 64) norm_s[tid] = (row0 + tid < nrows) ? norm[row0 + tid] : 0.f;
  __syncthreads();

  const int w = tid >> 6, lane = tid & 63;
  const int quad = lane >> 4, r16 = lane & 15;
  const int arow = w * 16 + r16;

  short8 a[4];
#pragma unroll
  for (int kc = 0; kc < 4; kc++)
    a[kc] = *(const short8*)&Xs[arow * XP + kc * 32 + quad * 8];

#pragma unroll
  for (int nc = 0; nc < 4; nc++) {
    floatx4 acc = {0.f, 0.f, 0.f, 0.f};
#pragma unroll
    for (int kc = 0; kc < 4; kc++) {
      short8 b = *(const short8*)&Wt[(nc * 16 + r16) * XP + kc * 32 + quad * 8];
      acc = __builtin_amdgcn_mfma_f32_16x16x32_bf16(a[kc], b, acc, 0, 0, 0);
    }
#pragma unroll
    for (int i = 0; i < 4; i++) {
      int lr = w * 16 + quad * 4 + i;     // C/D: row = quad*4+reg, col = r16
      int gr = row0 + lr;
      if (gr < nrows)
        Y[(size_t)gr * CTOT + col0 + nc * 16 + r16] = f2bf(acc[i] * norm_s[lr]);
    }
  }
}

// ---- gather helpers (2-stage pipelined 4-edge batches, 4-8 loads in flight) --

__device__ __forceinline__ void acc_row(float* acc, uint4 p) {
  acc[0] += __uint_as_float(p.x << 16);
  acc[1] += __uint_as_float(p.x & 0xffff0000u);
  acc[2] += __uint_as_float(p.y << 16);
  acc[3] += __uint_as_float(p.y & 0xffff0000u);
  acc[4] += __uint_as_float(p.z << 16);
  acc[5] += __uint_as_float(p.z & 0xffff0000u);
  acc[6] += __uint_as_float(p.w << 16);
  acc[7] += __uint_as_float(p.w & 0xffff0000u);
}

template <int F>
__device__ __forceinline__ void gather_acc(const u16* __restrict__ Hp,
                                           const int* __restrict__ csr,
                                           int beg, int end, float* acc) {
  int e = beg;
  int nfull = (end - beg) >> 2;
  if (nfull > 0) {
    int sv[4]; uint4 p[4];
#pragma unroll
    for (int j = 0; j < 4; j++) sv[j] = csr[e + j];
#pragma unroll
    for (int j = 0; j < 4; j++) p[j] = *(const uint4*)&Hp[(size_t)sv[j] * F];
    for (int b = 1; b < nfull; b++) {
      e += 4;
      int s2[4]; uint4 q[4];
#pragma unroll
      for (int j = 0; j < 4; j++) s2[j] = csr[e + j];
#pragma unroll
      for (int j = 0; j < 4; j++) q[j] = *(const uint4*)&Hp[(size_t)s2[j] * F];
#pragma unroll
      for (int j = 0; j < 4; j++) acc_row(acc, p[j]);
#pragma unroll
      for (int j = 0; j < 4; j++) p[j] = q[j];
    }
#pragma unroll
    for (int j = 0; j < 4; j++) acc_row(acc, p[j]);
    e += 4;
  }
  for (; e < end; e++) {
    uint4 p = *(const uint4*)&Hp[(size_t)csr[e] * F];
    acc_row(acc, p);
  }
}

// ---- FUSED spmm1 + gemm2: per 64-node tile, aggregate H -> relu -> T-tile in
// LDS -> MFMA with W2 -> H2. T never round-trips through memory (saves 154MB
// beyond-L2 traffic + one dispatch). Gather-phase and MFMA-phase blocks
// co-resident on a CU hide each other.

__global__ __launch_bounds__(256) void spmm1_gemm2_kernel(
    const u16* __restrict__ Hbase,
    const int* __restrict__ offsb, const int* __restrict__ degb,
    const int* __restrict__ csrb,
    const float* __restrict__ ndb, const float* __restrict__ b1,
    const float* __restrict__ W2, const float* __restrict__ nsb,
    u16* __restrict__ H2base, int n) {
  const int z = blockIdx.z;
  const u16* __restrict__ Hb = Hbase + (size_t)z * NH16;
  const int* __restrict__ offs = offsb + (size_t)z * NNODES;
  const int* __restrict__ deg = degb + (size_t)z * NNODES;
  const int* __restrict__ csr = csrb + (size_t)z * NEDGES;
  const float* __restrict__ nd = ndb + (size_t)z * NNODES;
  const float* __restrict__ ns = nsb + (size_t)z * NNODES;
  u16* __restrict__ H2 = H2base + (size_t)z * NH16;   // uses lower half of T[z]

  __shared__ u16 Ts[64 * XP];
  __shared__ u16 Wt[64 * XP];
  __shared__ float norm_s[64];
  const int tid = threadIdx.x;
  const int row0 = blockIdx.x * 64;

  // stage W2^T as bf16 (128 k x 64 cols)
  for (int i = tid; i < 128 * 16; i += 256) {
    int k = i >> 4, c4 = (i & 15) * 4;
    float4 v = *(const float4*)&W2[(size_t)k * FOUT + c4];
    Wt[(c4 + 0) * XP + k] = f2bf(v.x);
    Wt[(c4 + 1) * XP + k] = f2bf(v.y);
    Wt[(c4 + 2) * XP + k] = f2bf(v.z);
    Wt[(c4 + 3) * XP + k] = f2bf(v.w);
  }
  if (tid < 64) norm_s[tid] = (row0 + tid < n) ? ns[row0 + tid] : 0.f;

  // spmm phase: 64 nodes, 4 groups of 16, TPN=16 lanes (16B = 8 bf16 each)
  const int nsub = tid >> 4;          // 0..15 node-within-group
  const int f0 = (tid & 15) * 8;
  const u16* __restrict__ Hp = Hb + f0;
#pragma unroll
  for (int g = 0; g < 4; g++) {
    int r = g * 16 + nsub;
    int node = row0 + r;
    uint4 pk = make_uint4(0u, 0u, 0u, 0u);
    if (node < n) {
      float acc[8] = {};
      int beg = offs[node];
      gather_acc<FHID>(Hp, csr, beg, beg + deg[node], acc);
      float ndv = nd[node];
      float o[8];
#pragma unroll
      for (int i = 0; i < 8; i++)
        o[i] = fmaxf(fmaf(acc[i], ndv, b1[f0 + i]), 0.f);
      pk.x = (u32)f2bf(o[0]) | ((u32)f2bf(o[1]) << 16);
      pk.y = (u32)f2bf(o[2]) | ((u32)f2bf(o[3]) << 16);
      pk.z = (u32)f2bf(o[4]) | ((u32)f2bf(o[5]) << 16);
      pk.w = (u32)f2bf(o[6]) | ((u32)f2bf(o[7]) << 16);
    }
    *(uint4*)&Ts[r * XP + f0] = pk;
  }
  __syncthreads();

  // MFMA phase: (Ts @ W2) * norm_s -> H2 (64x64)
  const int w = tid >> 6, lane = tid & 63;
  const int quad = lane >> 4, r16 = lane & 15;
  const int arow = w * 16 + r16;
  short8 a[4];
#pragma unroll
  for (int kc = 0; kc < 4; kc++)
    a[kc] = *(const short8*)&Ts[arow * XP + kc * 32 + quad * 8];
#pragma unroll
  for (int nc = 0; nc < 4; nc++) {
    floatx4 acc = {0.f, 0.f, 0.f, 0.f};
#pragma unroll
    for (int kc = 0; kc < 4; kc++) {
      short8 b = *(const short8*)&Wt[(nc * 16 + r16) * XP + kc * 32 + quad * 8];
      acc = __builtin_amdgcn_mfma_f32_16x16x32_bf16(a[kc], b, acc, 0, 0, 0);
    }
#pragma unroll
    for (int i = 0; i < 4; i++) {
      int lr = w * 16 + quad * 4 + i;
      int gr = row0 + lr;
      if (gr < n)
        H2[(size_t)gr * FOUT + nc * 16 + r16] = f2bf(acc[i] * norm_s[lr]);
    }
  }
}

// ---- SpMM (layer 2): z[n,:] = (sum Hb2[src[e],:]) * nd[n] + b2, fp32 out ----

template <int F, bool RELU, bool OUT_BF16>
__global__ __launch_bounds__(256) void spmm_bf16(const u16* __restrict__ Hbase,
                                                 const int* __restrict__ offsb,
                                                 const int* __restrict__ degb,
                                                 const int* __restrict__ csrb,
                                                 const float* __restrict__ ndb,
                                                 const float* __restrict__ bias,
                                                 void* __restrict__ Yv, int n) {
  const int z = blockIdx.z;
  const u16* __restrict__ Hb = Hbase + (size_t)z * NH16;   // NH16 slice stride
  const int* __restrict__ offs = offsb + (size_t)z * NNODES;
  const int* __restrict__ deg = degb + (size_t)z * NNODES;
  const int* __restrict__ csr = csrb + (size_t)z * NEDGES;
  const float* __restrict__ norm_dst = ndb + (size_t)z * NNODES;
  constexpr int TPN = F / 8;
  constexpr int NPB = 256 / TPN;
  int node = blockIdx.x * NPB + threadIdx.x / TPN;
  if (node >= n) return;
  int f0 = (threadIdx.x % TPN) * 8;
  int beg = offs[node];
  float acc[8] = {};
  gather_acc<F>(Hb + f0, csr, beg, beg + deg[node], acc);
  float nd = norm_dst[node];
  float o[8];
#pragma unroll
  for (int i = 0; i < 8; i++) {
    o[i] = fmaf(acc[i], nd, bias[f0 + i]);
    if (RELU) o[i] = fmaxf(o[i], 0.f);
  }
  if constexpr (OUT_BF16) {
    u16* Y = (u16*)Yv + (size_t)z * NNODES * F;
    uint4 pk;
    pk.x = (u32)f2bf(o[0]) | ((u32)f2bf(o[1]) << 16);
    pk.y = (u32)f2bf(o[2]) | ((u32)f2bf(o[3]) << 16);
    pk.z = (u32)f2bf(o[4]) | ((u32)f2bf(o[5]) << 16);
    pk.w = (u32)f2bf(o[6]) | ((u32)f2bf(o[7]) << 16);
    *(uint4*)&Y[(size_t)node * F + f0] = pk;
  } else {
    float* Y = (float*)Yv + (size_t)z * NNODES * F;
    *(float4*)&Y[(size_t)node * F + f0] = make_float4(o[0], o[1], o[2], o[3]);
    *(float4*)&Y[(size_t)node * F + f0 + 4] = make_float4(o[4], o[5], o[6], o[7]);
  }
}

// ---------------- driver ----------------
// 7 launches, all batched over the 3 graphs via gridDim.z=3; ws_size-guarded
// fallback runs the same kernels per graph.

extern "C" void kernel_launch(void* const* d_in, const int* in_sizes, int n_in,
                              void* d_out, int out_size, void* d_ws, size_t ws_size,
                              hipStream_t stream) {
  const int N = NNODES;
  const int E = NEDGES;
  const float* W1 = (const float*)d_in[9];
  const float* b1 = (const float*)d_in[10];
  const float* W2 = (const float*)d_in[11];
  const float* b2 = (const float*)d_in[12];

  const size_t HBYTES = NH16 * 2;   // 25.6 MB per graph

  auto need_for = [&](size_t NG) -> size_t {
    size_t o = 0;
    auto al = [&](size_t b) { o = (o + b + 255) & ~(size_t)255; };
    al(NG * N * 4);        // deg_dst
    al(NG * N * 4);        // norm_src
    al(NG * N * 4);        // norm_dst
    al(NG * N * 4);        // offs
    al(NG * NBUK * 4);     // boff
    al(NG * NBUK * 4);     // bcount
    al(NG * NBUK * 4);     // boff_s
    al(NG * NBUK * 4);     // bcount_s
    al(NG * (size_t)E * 4);// csr
    al(NG * HBYTES);       // H
    al(NG * HBYTES);       // T (pe scratch, then H2)
    return o;
  };
  const bool batched = ws_size >= need_for(3);
  const size_t NG = batched ? 3 : 1;

  char* ws = (char*)d_ws;
  size_t off = 0;
  auto alloc = [&](size_t bytes) -> void* {
    void* p = ws + off;
    off += (bytes + 255) & ~(size_t)255;
    return p;
  };
  int* deg_dst = (int*)alloc(NG * N * 4);
  float* norm_src = (float*)alloc(NG * N * 4);
  float* norm_dst = (float*)alloc(NG * N * 4);
  int* offs = (int*)alloc(NG * N * 4);
  u32* boff = (u32*)alloc(NG * NBUK * 4);
  u32* bcount = (u32*)alloc(NG * NBUK * 4);
  u32* boff_s = (u32*)alloc(NG * NBUK * 4);
  u32* bcount_s = (u32*)alloc(NG * NBUK * 4);
  int* csr = (int*)alloc(NG * (size_t)E * 4);
  u16* H = (u16*)alloc(NG * HBYTES);
  u16* T = (u16*)alloc(NG * HBYTES);

  const int gemm_rb = (N + 63) / 64;    // 1563
  const int nb2 = (N + 31) / 32;        // 3125 (F=64: 32 nodes/block)

  auto run = [&](const int* s0, const int* s1, const int* s2,
                 const int* d0, const int* d1, const int* d2,
                 const float* f0, const float* f1, const float* f2,
                 void* zoutv, unsigned gz) {
    bucket_hist_kernel<<<dim3(NSL2, 1, gz), 256, 0, stream>>>(s0, s1, s2, d0, d1, d2, H, E);
    scan_part_kernel<<<dim3(2, 1, gz), 512, 0, stream>>>(H, boff, bcount, boff_s, bcount_s);
    scatter_kernel<<<dim3(NSL2, 1, gz), 256, 0, stream>>>(s0, s1, s2, d0, d1, d2,
                                                          H, T, boff, boff_s, E);
    bucket_finish_kernel<<<dim3(NBUK, 2, gz), 256, 0, stream>>>(
        T, H, boff, bcount, boff_s, bcount_s, csr, offs, deg_dst, norm_dst,
        norm_src, N);
    // layer 1 gemm: H = bf16((feat @ W1)*norm_src)
    gemm_mfma<FHID, false><<<dim3(gemm_rb, FHID / 64, gz), 256, 0, stream>>>(
        f0, f1, f2, W1, norm_src, H, N);
    // fused layer-1 spmm + layer-2 gemm: H2 (in T) = bf16(ns * (relu(spmm(H)*nd+b1) @ W2))
    spmm1_gemm2_kernel<<<dim3(gemm_rb, 1, gz), 256, 0, stream>>>(
        H, offs, deg_dst, csr, norm_dst, b1, W2, norm_src, T, N);
    // layer 2 spmm: z = spmm(H2)*nd + b2 (fp32)
    spmm_bf16<FOUT, false, false><<<dim3(nb2, 1, gz), 256, 0, stream>>>(
        T, offs, deg_dst, csr, norm_dst, b2, zoutv, N);
  };

  if (batched) {
    run((const int*)d_in[1], (const int*)d_in[4], (const int*)d_in[7],
        (const int*)d_in[2], (const int*)d_in[5], (const int*)d_in[8],
        (const float*)d_in[0], (const float*)d_in[3], (const float*)d_in[6],
        d_out, 3);
  } else {
    for (int g = 0; g < 3; g++) {
      const float* feat = (const float*)d_in[3 * g + 0];
      const int* src = (const int*)d_in[3 * g + 1];
      const int* dst = (const int*)d_in[3 * g + 2];
      float* zout = (float*)d_out + (size_t)g * N * FOUT;
      run(src, src, src, dst, dst, dst, feat, feat, feat, zout, 1);
    }
  }
}